// Round 11
// baseline (425.307 us; speedup 1.0000x reference)
//
#include <hip/hip_runtime.h>
#include <hip/hip_bf16.h>

#define B_ 4096
#define D_ 32
#define H_ 1024
#define WPK2_L 1171456         // shorts per padded layer pack (2048 * 572)

typedef __attribute__((ext_vector_type(8))) short short8;
typedef __attribute__((ext_vector_type(4))) float floatx4;

__device__ inline unsigned short f2bf(float f) {      // fp32 -> bf16 bits, RNE
    unsigned u = __float_as_uint(f);
    unsigned r = (u + 0x7FFF + ((u >> 16) & 1)) >> 16;
    return (unsigned short)r;
}

// degree-sorted order: degree 0 -> slots [0,34), degree d>=1 -> slots [33d+1, 33d+34)
__device__ inline int degs(int hp) { return (hp < 34) ? 0 : (hp - 1) / 33; }
__device__ inline int permf(int hp) {                  // sorted slot -> original h
    int d = degs(hp);
    int r = d ? (hp - 33 * d - 1) : hp;
    return d + 31 * r;
}
__device__ inline int band0i(int idx) {                // fresh-band base slot at step idx>=1
    int nb0 = (idx == 1) ? 0 : 33 * idx - 32;
    return (nb0 > H_ - 64) ? H_ - 64 : nb0;
}

// ---- prep stage 1 (fused): permuted+masked Wbp, W0 packs, compact Wout packs, biases ----
__global__ __launch_bounds__(256) void prep1(
        const float* __restrict__ Wh, const float* __restrict__ W0,
        const float* __restrict__ Wout, const float* __restrict__ b0,
        const float* __restrict__ bh,
        unsigned short* __restrict__ Wbp, unsigned short* __restrict__ W0pk,
        unsigned short* __restrict__ Wopk, float* __restrict__ b0p,
        float* __restrict__ bhp) {
    __shared__ float row[H_];
    int b = blockIdx.x, t = threadIdx.x;
    if (b < 2048) {                          // Wbp[l][np][kp], staged via LDS (coalesced)
        int l = b >> 10, np = b & 1023;
        const float* src = Wh + ((size_t)l << 20) + ((size_t)permf(np) << 10);
        ((float4*)row)[t] = ((const float4*)src)[t];
        __syncthreads();
        int dn = degs(np);
        unsigned short o[4];
        #pragma unroll
        for (int j = 0; j < 4; j++) {
            int kp = t * 4 + j;
            o[j] = (dn >= degs(kp)) ? f2bf(row[permf(kp)]) : (unsigned short)0;
        }
        ((ushort4*)(Wbp + ((size_t)l << 20) + ((size_t)np << 10)))[t] =
            ushort4{o[0], o[1], o[2], o[3]};
    } else if (b < 2079) {                   // W0 band packs [idx][slot64][32]
        int idx = b - 2047;
        int nb0 = band0i(idx);
        int j = t >> 2, ko = (t & 3) * 8;
        int n = nb0 + j;
        int dn = degs(n);
        const float* srow = W0 + (size_t)permf(n) * 32;
        union { unsigned short o[8]; uint4 v; } u;
        #pragma unroll
        for (int e = 0; e < 8; e++)
            u.o[e] = (dn >= ko + e) ? f2bf(srow[ko + e]) : (unsigned short)0;
        *(uint4*)(W0pk + (idx - 1) * 2048 + j * 32 + ko) = u.v;
    } else if (b < 2335) {                   // compact Wout packs [idx][c][2 cols][32]
        int e = (b - 2079) * 256 + t;        // over 32*32*64
        int idx = e >> 11, c = (e >> 6) & 31, col = (e >> 5) & 1, k = e & 31;
        int ns = idx ? 33 * idx + 1 : 0;
        int h = c * 32 + k;
        unsigned short v = 0;
        if (h < ns) v = f2bf(Wout[(size_t)(idx + col * 32) * H_ + permf(h)]);
        Wopk[e] = v;
    } else {                                 // biases
        int tt = (b - 2335) * 256 + t;       // over 3*1024
        int hp = tt & 1023;
        int p = permf(hp);
        if (tt < 1024) b0p[hp] = b0[p];
        else if (tt < 2048) bhp[hp] = bh[p];
        else bhp[1024 + hp] = bh[1024 + p];
    }
}

// ---- prep stage 2: repack Wbp -> zero-padded per-step band packs [c][slot64][32] ----
// nk4(idx) = 4*ceil((idx+1)/4) chunks; chunks beyond idx are all-zero (exact).
__global__ __launch_bounds__(256) void prep2(const unsigned short* __restrict__ Wbp,
                                             unsigned short* __restrict__ Wpk) {
    int b = blockIdx.x;                      // 2 layers * 31 idx * 32 chunk slots
    int l = b / 992;
    int r = b - l * 992;
    int idx = (r >> 5) + 1;
    int c = r & 31;
    int Cn = (idx + 4) >> 2;                 // ceil((idx+1)/4)
    if (c >= 4 * Cn) return;
    int S = 0;
    for (int j = 1; j < idx; j++) S += (j + 4) >> 2;
    size_t base = (size_t)l * WPK2_L + (size_t)S * 4 * 2048 + (size_t)c * 2048;
    int t = threadIdx.x;
    int j = t >> 2, ko = (t & 3) * 8;
    uint4 v = {0u, 0u, 0u, 0u};
    if (c <= idx) {
        int nb0 = band0i(idx);
        v = *(const uint4*)(Wbp + ((size_t)l << 20) + ((size_t)(nb0 + j) << 10) + c * 32 + ko);
    }
    *(uint4*)(Wpk + base + j * 32 + ko) = v;
}

__device__ inline floatx4 mfma16(short8 a, short8 b, floatx4 c) {
    return __builtin_amdgcn_mfma_f32_16x16x32_bf16(a, b, c, 0, 0, 0);
}

// ---- one hidden layer band: 16 rows x 64 slots over nk4 chunks, single wave ----
// Depth-4 register ring prefetch of weights (compile-time ring index, no guards).
__device__ __forceinline__ void layer_band(
        const unsigned short* __restrict__ aPrev,   // LDS [c][16][32] + (frow*32+fk*8)
        unsigned short* __restrict__ aNext,         // LDS base of next buffer
        const unsigned short* __restrict__ wpk,     // padded pack for this (layer, idx)
        const float* __restrict__ bias, int nb0, int nk4,
        int frow, int fk, int woff) {
    floatx4 acc[4] = {};
    short8 W[4][4];
    #pragma unroll
    for (int u = 0; u < 4; u++)
        #pragma unroll
        for (int s = 0; s < 4; s++)
            W[u][s] = *(const short8*)(wpk + (size_t)u * 2048 + s * 512 + woff);
    for (int c4 = 0; c4 < nk4; c4 += 4) {
        #pragma unroll
        for (int u = 0; u < 4; u++) {
            int c = c4 + u;
            short8 a = *(const short8*)(aPrev + c * 512);
            #pragma unroll
            for (int s = 0; s < 4; s++)
                acc[s] = mfma16(a, W[u][s], acc[s]);
            int cn = c + 4;
            if (cn < nk4) {
                #pragma unroll
                for (int s = 0; s < 4; s++)
                    W[u][s] = *(const short8*)(wpk + (size_t)cn * 2048 + s * 512 + woff);
            }
        }
    }
    #pragma unroll
    for (int s = 0; s < 4; s++) {
        int sl = nb0 + s * 16 + frow;
        float bb = bias[sl];
        int wsl = (sl >> 5) * 512 + (sl & 31);
        #pragma unroll
        for (int r = 0; r < 4; r++)
            aNext[wsl + (fk * 4 + r) * 32] = f2bf(fmaxf(acc[s][r] + bb, 0.f));
    }
}

// ---- mega-kernel: 256 wgs x ONE wave x 16 rows; zero barriers ----
__global__ void mega_kernel(
        const float* __restrict__ z,
        const unsigned short* __restrict__ W0pk,
        const float* __restrict__ b0p,
        const unsigned short* __restrict__ Wpk,
        const float* __restrict__ bhp,
        const unsigned short* __restrict__ Wopk,
        const float* __restrict__ bout,
        float* __restrict__ xout) {
    __shared__ unsigned short aS[3 * 32 * 512];    // a1,a2,a3: [c][16 rows][32], 32KB each
    __shared__ unsigned short xbS[512];            // running x bf16 [m][32]
    __shared__ float xsS[512];                     // running x fp32
    __shared__ float zsS[512];
    __shared__ float thS[32];                      // theta: [0..15]=mu, [16..31]=log_std

    const int lane = threadIdx.x & 63;
    const int frow = lane & 15, fk = lane >> 4;
    const int foff = frow * 32 + fk * 8;
    const int m0 = blockIdx.x * 16;

    {   // zero-init (garbage x 0-weight must stay 0; matches x0 = 0)
        uint4 zz = {0u, 0u, 0u, 0u};
        #pragma unroll
        for (int i = 0; i < 96; i++) ((uint4*)aS)[i * 64 + lane] = zz;
        ((uint4*)xbS)[lane] = zz;
        if (lane < 32) { ((uint4*)xsS)[lane] = zz; ((uint4*)(xsS + 128))[lane] = zz; }
        ((float4*)zsS)[lane] = ((const float4*)(z + (size_t)m0 * 32))[lane];
        ((float4*)zsS)[lane + 64] = ((const float4*)(z + (size_t)m0 * 32))[lane + 64];
    }
    __syncthreads();

    unsigned short* a1 = aS;
    unsigned short* a2 = aS + 32 * 512;
    unsigned short* a3 = aS + 64 * 512;

    // idx = 0: theta = bias
    if (lane < 16) {
        float xi = fmaf(zsS[lane * 32], expf(bout[D_]), bout[0]);
        xsS[lane * 32] = xi;
        xbS[lane * 32] = f2bf(xi);
    }

    int wbase = 0;
    for (int idx = 1; idx < 32; idx++) {
        const int nb0 = band0i(idx);
        const int nk  = idx + 1;
        const int nk4 = (nk + 3) & ~3;

        // ---- layer 1 band: K=32, 4 N-tiles ----
        {
            short8 xa = *(const short8*)(xbS + foff);
            #pragma unroll
            for (int s = 0; s < 4; s++) {
                short8 wb = *(const short8*)(W0pk + (idx - 1) * 2048 + (s * 16 + frow) * 32 + fk * 8);
                floatx4 acc = {};
                acc = mfma16(xa, wb, acc);
                int sl = nb0 + s * 16 + frow;
                float bb = b0p[sl];
                int wsl = (sl >> 5) * 512 + (sl & 31);
                #pragma unroll
                for (int r = 0; r < 4; r++)
                    a1[wsl + (fk * 4 + r) * 32] = f2bf(fmaxf(acc[r] + bb, 0.f));
            }
        }

        // ---- layers 2 and 3 ----
        const unsigned short* wl2 = Wpk + wbase;
        layer_band(a1 + foff, a2, wl2,          bhp,      nb0, nk4, frow, fk, foff);
        layer_band(a2 + foff, a3, wl2 + WPK2_L, bhp + H_, nb0, nk4, frow, fk, foff);

        // ---- out-dot: theta cols idx/idx+32 over live a3 chunks ----
        {
            floatx4 oacc = {};
            for (int c = 0; c < nk; c++) {
                short8 a = *(const short8*)(a3 + c * 512 + foff);
                short8 w = {};
                if (frow < 2)
                    w = *(const short8*)(Wopk + (size_t)(idx * 32 + c) * 64 + frow * 32 + fk * 8);
                oacc = mfma16(a, w, oacc);
            }
            if (frow < 2) {
                #pragma unroll
                for (int r = 0; r < 4; r++)
                    thS[frow * 16 + fk * 4 + r] = oacc[r];
            }
            if (lane < 16) {
                float mu = thS[lane] + bout[idx];
                float ls = thS[16 + lane] + bout[idx + D_];
                float xi = fmaf(zsS[lane * 32 + idx], expf(ls), mu);
                xsS[lane * 32 + idx] = xi;
                xbS[lane * 32 + idx] = f2bf(xi);
            }
        }
        wbase += ((idx + 4) >> 2) * 4 * 2048;
    }

    ((float4*)(xout + (size_t)m0 * 32))[lane] = ((const float4*)xsS)[lane];
    ((float4*)(xout + (size_t)m0 * 32))[lane + 64] = ((const float4*)xsS)[lane + 64];
}

extern "C" void kernel_launch(void* const* d_in, const int* in_sizes, int n_in,
                              void* d_out, int out_size, void* d_ws, size_t ws_size,
                              hipStream_t stream) {
    const float* z    = (const float*)d_in[0];
    const float* W0   = (const float*)d_in[1];
    const float* b0   = (const float*)d_in[2];
    const float* Wh   = (const float*)d_in[3];   // [2, H, H]
    const float* bh   = (const float*)d_in[4];   // [2, H]
    const float* Wout = (const float*)d_in[5];   // [64, H]
    const float* bout = (const float*)d_in[6];   // [64]

    float* x = (float*)d_out;                          // [B, D] output
    unsigned short* Wbp  = (unsigned short*)d_ws;      // [2, H, H] permuted+masked bf16
    unsigned short* Wpk  = Wbp + 2 * H_ * H_;          // 2 * WPK2_L padded band packs
    unsigned short* W0pk = Wpk + 2 * WPK2_L;           // 31 * 2048
    unsigned short* Wopk = W0pk + 31 * 2048;           // 32 * 32 * 64 compact out packs
    float* b0p = (float*)(Wopk + 32 * 32 * 64);        // [H]
    float* bhp = b0p + H_;                             // [2, H]

    prep1<<<2347, 256, 0, stream>>>(Wh, W0, Wout, b0, bh, Wbp, W0pk, Wopk, b0p, bhp);
    prep2<<<2 * 31 * 32, 256, 0, stream>>>(Wbp, Wpk);

    mega_kernel<<<B_ / 16, 64, 0, stream>>>(z, W0pk, b0p, Wpk, bhp, Wopk, bout, x);
}

// Round 12
// 220.368 us; speedup vs baseline: 1.9300x; 1.9300x over previous
//
#include <hip/hip_runtime.h>
#include <hip/hip_bf16.h>

#define B_ 4096
#define D_ 32
#define H_ 1024
#define CS 512                 // activation chunk stride: [chunk][16 rows][32] shorts
#define WPK_L 1079296          // shorts per hidden-layer weight pack (= 2048*sum(idx+1))

typedef __attribute__((ext_vector_type(8))) short short8;
typedef __attribute__((ext_vector_type(4))) float floatx4;

// non-draining workgroup barrier: LDS visibility only, leaves global loads in flight
#define BAR() __asm__ __volatile__("s_waitcnt lgkmcnt(0)\n\ts_barrier" ::: "memory")

__device__ inline unsigned short f2bf(float f) {      // fp32 -> bf16 bits, RNE
    unsigned u = __float_as_uint(f);
    unsigned r = (u + 0x7FFF + ((u >> 16) & 1)) >> 16;
    return (unsigned short)r;
}
__device__ inline void glds16(const void* g, void* l) {
    __builtin_amdgcn_global_load_lds(
        (const __attribute__((address_space(1))) unsigned int*)g,
        (__attribute__((address_space(3))) unsigned int*)l, 16, 0, 0);
}

// degree-sorted order: degree 0 -> slots [0,34), degree d>=1 -> slots [33d+1, 33d+34)
__device__ inline int degs(int hp) { return (hp < 34) ? 0 : (hp - 1) / 33; }
__device__ inline int permf(int hp) {                  // sorted slot -> original h
    int d = degs(hp);
    int r = d ? (hp - 33 * d - 1) : hp;
    return d + 31 * r;
}
__device__ inline int band0i(int idx) {                // fresh-band base slot at step idx>=1
    int nb0 = (idx == 1) ? 0 : 33 * idx - 32;
    return (nb0 > H_ - 64) ? H_ - 64 : nb0;
}

// ---- prep stage 1 (fused): permuted+masked Wbp, W0 packs, Wout packs, biases ----
__global__ __launch_bounds__(256) void prep1(
        const float* __restrict__ Wh, const float* __restrict__ W0,
        const float* __restrict__ Wout, const float* __restrict__ b0,
        const float* __restrict__ bh,
        unsigned short* __restrict__ Wbp, unsigned short* __restrict__ W0pk,
        unsigned short* __restrict__ Wopk, float* __restrict__ b0p,
        float* __restrict__ bhp) {
    __shared__ float row[H_];
    int b = blockIdx.x, t = threadIdx.x;
    if (b < 2048) {                          // Wbp[l][np][kp], staged via LDS (coalesced)
        int l = b >> 10, np = b & 1023;
        const float* src = Wh + ((size_t)l << 20) + ((size_t)permf(np) << 10);
        ((float4*)row)[t] = ((const float4*)src)[t];
        __syncthreads();
        int dn = degs(np);
        unsigned short o[4];
        #pragma unroll
        for (int j = 0; j < 4; j++) {
            int kp = t * 4 + j;
            o[j] = (dn >= degs(kp)) ? f2bf(row[permf(kp)]) : (unsigned short)0;
        }
        ((ushort4*)(Wbp + ((size_t)l << 20) + ((size_t)np << 10)))[t] =
            ushort4{o[0], o[1], o[2], o[3]};
    } else if (b < 2079) {                   // W0 band packs [idx][slot64][32]
        int idx = b - 2047;
        int nb0 = band0i(idx);
        int j = t >> 2, ko = (t & 3) * 8;
        int n = nb0 + j;
        int dn = degs(n);
        const float* srow = W0 + (size_t)permf(n) * 32;
        union { unsigned short o[8]; uint4 v; } u;
        #pragma unroll
        for (int e = 0; e < 8; e++)
            u.o[e] = (dn >= ko + e) ? f2bf(srow[ko + e]) : (unsigned short)0;
        *(uint4*)(W0pk + (idx - 1) * 2048 + j * 32 + ko) = u.v;
    } else if (b < 3103) {                   // Wout bf16 packs [idx][c][col16][32]
        int bb = b - 2079;
        int idx = bb >> 5, c = bb & 31;
        int ns = idx ? 33 * idx + 1 : 0;     // live-prefix length at step idx
        #pragma unroll
        for (int uu = 0; uu < 2; uu++) {
            int e = t + uu * 256;
            int col = e >> 5, k = e & 31;
            int h = c * 32 + k;
            unsigned short v = 0;
            if (col < 2 && h < ns)
                v = f2bf(Wout[(size_t)(idx + col * 32) * H_ + permf(h)]);
            Wopk[(size_t)bb * 512 + e] = v;
        }
    } else {                                 // biases
        int tt = (b - 3103) * 256 + t;       // over 3*1024
        int hp = tt & 1023;
        int p = permf(hp);
        if (tt < 1024) b0p[hp] = b0[p];
        else if (tt < 2048) bhp[hp] = bh[p];
        else bhp[1024 + hp] = bh[1024 + p];
    }
}

// ---- prep stage 2: contiguous repack Wbp -> per-step band packs [c][slot64][32] ----
__global__ __launch_bounds__(256) void prep2(const unsigned short* __restrict__ Wbp,
                                             unsigned short* __restrict__ Wpk) {
    int b = blockIdx.x;                      // 2 layers * 31 idx * 32 chunk slots
    int l = b / 992;
    int r = b - l * 992;
    int idx = (r >> 5) + 1;
    int c = r & 31;
    if (c >= idx + 1) return;                // nk(idx) = idx+1 live chunks
    int nb0 = band0i(idx);
    int t = threadIdx.x;
    int j = t >> 2, ko = (t & 3) * 8;
    uint4 v = *(const uint4*)(Wbp + ((size_t)l << 20) + ((size_t)(nb0 + j) << 10) + c * 32 + ko);
    *(uint4*)(Wpk + (size_t)l * WPK_L + (size_t)1024 * (idx - 1) * (idx + 2)
              + c * 2048 + j * 32 + ko) = v;
}

__device__ inline floatx4 mfma16(short8 a, short8 b, floatx4 c) {
    return __builtin_amdgcn_mfma_f32_16x16x32_bf16(a, b, c, 0, 0, 0);
}

// ---- band K-partial: one wave, 16 slots x 16 rows, chunks [c0,c1) ----
__device__ inline floatx4 band_partial(const unsigned short* act, const unsigned short* wpk,
                                       int frow, int fk, int s, int c0, int c1) {
    const unsigned short* ap = act + frow * 32 + fk * 8;
    const unsigned short* wp = wpk + s * 512 + frow * 32 + fk * 8;
    floatx4 x = {0.f, 0.f, 0.f, 0.f}, y = {0.f, 0.f, 0.f, 0.f};
    int c = c0;
    for (; c + 1 < c1; c += 2) {
        short8 a0 = *(const short8*)(ap + c * CS);
        short8 b0 = *(const short8*)(wp + (size_t)c * 2048);
        short8 a1 = *(const short8*)(ap + (c + 1) * CS);
        short8 b1 = *(const short8*)(wp + (size_t)(c + 1) * 2048);
        x = mfma16(a0, b0, x);
        y = mfma16(a1, b1, y);
    }
    if (c < c1) {
        short8 a0 = *(const short8*)(ap + c * CS);
        short8 b0 = *(const short8*)(wp + (size_t)c * 2048);
        x = mfma16(a0, b0, x);
    }
    return x + y;
}

// ---- mega-kernel: 256 wgs x 16 rows x 16 waves; 32-step chain in LDS ----
__global__ __launch_bounds__(1024) void mega_kernel(
        const float* __restrict__ z,
        const unsigned short* __restrict__ W0pk,
        const float* __restrict__ b0p,
        const unsigned short* __restrict__ Wpk,
        const float* __restrict__ bhp,
        const unsigned short* __restrict__ Wopk,
        const float* __restrict__ bout,
        float* __restrict__ xout) {
    __shared__ unsigned short aS[3 * 32 * CS];     // a1,a2,a3: [c][16 rows][32], 32KB each
    __shared__ unsigned short xbS[16 * 32];        // running x, bf16
    __shared__ float xsS[512];                     // running x, fp32
    __shared__ float zsS[512];
    __shared__ floatx4 redS[12 * 64];              // K-split partials [q-1][s][lane]
    __shared__ float redO[16 * 32];                // out-dot partials [wave][col*16+m]
    __shared__ uint4 dummyS[64];                   // prefetch sink (never read)

    const int tid = threadIdx.x;
    const int wave = tid >> 6, lane = tid & 63;
    const int frow = lane & 15, fk = lane >> 4;
    const int arow = frow * 32 + fk * 8;
    const int s = wave & 3, q = wave >> 2;
    const int m0 = blockIdx.x * 16;

    {   // zero-init (garbage x 0-weight must stay 0; matches x0 = 0)
        uint4 zz = {0u, 0u, 0u, 0u};
        for (int i = tid; i < 3 * 32 * CS / 8; i += 1024) ((uint4*)aS)[i] = zz;
        if (tid < 64)  ((uint4*)xbS)[tid] = zz;
        if (tid < 128) ((uint4*)xsS)[tid] = zz;
        if (tid < 128) ((uint4*)redO)[tid] = zz;
        if (tid < 128) ((float4*)zsS)[tid] = ((const float4*)(z + (size_t)m0 * 32))[tid];
    }
    __syncthreads();

    unsigned short* a1 = aS;
    unsigned short* a2 = aS + 32 * CS;
    unsigned short* a3 = aS + 64 * CS;

    for (int idx = 0; idx < 32; idx++) {
        if (idx > 0) {
            const int nb0 = band0i(idx);
            const int slot = nb0 + s * 16 + frow;
            const int nk = idx + 1;
            const int nk4 = (nk + 3) >> 2;
            const int c0 = q * nk4;
            const int c1m = (c0 + nk4 < nk) ? c0 + nk4 : nk;
            const unsigned short* wb2 = Wpk + (size_t)1024 * (idx - 1) * (idx + 2);
            const unsigned short* wb3 = wb2 + WPK_L;
            const int wsl = (slot >> 5) * CS + (slot & 31);

            // ---- layer 1 band (q==0): K=32 single chunk ----
            if (q == 0) {
                short8 a = *(const short8*)(xbS + frow * 32 + fk * 8);
                short8 bf = *(const short8*)(W0pk + (idx - 1) * 2048 + (s * 16 + frow) * 32 + fk * 8);
                floatx4 acc = {0.f, 0.f, 0.f, 0.f};
                acc = mfma16(a, bf, acc);
                float bb = b0p[slot];
                #pragma unroll
                for (int r = 0; r < 4; r++)
                    a1[wsl + (fk * 4 + r) * 32] = f2bf(fmaxf(acc[r] + bb, 0.f));
            }
            BAR();                                         // A: a1 visible

            // ---- layer 2 band ----
            {
                floatx4 p = band_partial(a1, wb2, frow, fk, s, c0, c1m);
                if (q) redS[((q - 1) * 4 + s) * 64 + lane] = p;
                BAR();                                     // B: partials visible
                if (q == 0) {
                    p = p + redS[s * 64 + lane] + redS[(4 + s) * 64 + lane]
                          + redS[(8 + s) * 64 + lane];
                    float bb = bhp[slot];
                    #pragma unroll
                    for (int r = 0; r < 4; r++)
                        a2[wsl + (fk * 4 + r) * 32] = f2bf(fmaxf(p[r] + bb, 0.f));
                }
                BAR();                                     // C: a2 visible
            }

            // ---- layer 3 band ----
            {
                floatx4 g = band_partial(a2, wb3, frow, fk, s, c0, c1m);
                if (q) redS[((q - 1) * 4 + s) * 64 + lane] = g;
                BAR();                                     // D: partials visible
                if (q == 0) {
                    g = g + redS[s * 64 + lane] + redS[(4 + s) * 64 + lane]
                          + redS[(8 + s) * 64 + lane];
                    float bb = bhp[H_ + slot];
                    #pragma unroll
                    for (int r = 0; r < 4; r++)
                        a3[wsl + (fk * 4 + r) * 32] = f2bf(fmaxf(g[r] + bb, 0.f));
                }
                BAR();                                     // E: a3 visible
            }
        }

        // ---- out-dot: wave w covers a3 chunks {2w, 2w+1}; dead-chunk weights are zero ----
        {
            floatx4 oacc = {0.f, 0.f, 0.f, 0.f};
            #pragma unroll
            for (int cc = 0; cc < 2; cc++) {
                int c = wave * 2 + cc;
                short8 a = *(const short8*)(a3 + c * CS + arow);
                short8 bf = *(const short8*)(Wopk + (size_t)((idx * 32 + c) * 16 + frow) * 32 + fk * 8);
                oacc = mfma16(a, bf, oacc);
            }
            if (frow < 2) {
                #pragma unroll
                for (int r = 0; r < 4; r++)
                    redO[wave * 32 + frow * 16 + fk * 4 + r] = oacc[r];
            }
        }

        // ---- L2-warming prefetch of step idx+1 packs (fire-and-forget; issued last) ----
        if (idx < 31) {
            const int slice = (blockIdx.x >> 3) & 31;      // 32 WGs/XCD tile the pack
            const char* w2n = (const char*)(Wpk + (size_t)1024 * idx * (idx + 3));
            const char* w3n = w2n + (size_t)WPK_L * 2;
            const int bytesn = (idx + 2) * 4096;
            const char* won = (const char*)(Wopk + (size_t)(idx + 1) * 32 * 512);
            int off = (slice & 7) * 16384;
            if (off < bytesn) {
                glds16(w2n + off + tid * 16, dummyS);
                glds16(w3n + off + tid * 16, dummyS);
            }
            glds16(won + (slice & 1) * 16384 + tid * 16, dummyS);
        }
        BAR();                                             // F: redO visible

        if (tid < 16) {
            float sm = bout[idx], sl = bout[idx + D_];
            #pragma unroll
            for (int w = 0; w < 16; w++) {
                sm += redO[w * 32 + tid];
                sl += redO[w * 32 + 16 + tid];
            }
            float xi = fmaf(zsS[tid * 32 + idx], expf(sl), sm);
            xsS[tid * 32 + idx] = xi;
            xbS[tid * 32 + idx] = f2bf(xi);
        }
        BAR();                                             // G: x visible
    }

    __syncthreads();
    if (tid < 128)
        ((float4*)(xout + (size_t)m0 * 32))[tid] = ((const float4*)xsS)[tid];
}

extern "C" void kernel_launch(void* const* d_in, const int* in_sizes, int n_in,
                              void* d_out, int out_size, void* d_ws, size_t ws_size,
                              hipStream_t stream) {
    const float* z    = (const float*)d_in[0];
    const float* W0   = (const float*)d_in[1];
    const float* b0   = (const float*)d_in[2];
    const float* Wh   = (const float*)d_in[3];   // [2, H, H]
    const float* bh   = (const float*)d_in[4];   // [2, H]
    const float* Wout = (const float*)d_in[5];   // [64, H]
    const float* bout = (const float*)d_in[6];   // [64]

    float* x = (float*)d_out;                          // [B, D] output
    unsigned short* Wbp  = (unsigned short*)d_ws;      // [2, H, H] permuted+masked bf16
    unsigned short* Wpk  = Wbp + 2 * H_ * H_;          // 2 * WPK_L band packs
    unsigned short* W0pk = Wpk + 2 * WPK_L;            // 31 * 2048
    unsigned short* Wopk = W0pk + 31 * 2048;           // 32 * 32 * 512
    float* b0p = (float*)(Wopk + 32 * 32 * 512);       // [H]
    float* bhp = b0p + H_;                             // [2, H]

    prep1<<<3115, 256, 0, stream>>>(Wh, W0, Wout, b0, bh, Wbp, W0pk, Wopk, b0p, bhp);
    prep2<<<2 * 31 * 32, 256, 0, stream>>>(Wbp, Wpk);

    mega_kernel<<<B_ / 16, 1024, 0, stream>>>(z, W0pk, b0p, Wpk, bhp, Wopk, bout, x);
}